// Round 5
// baseline (245.386 us; speedup 1.0000x reference)
//
#include <hip/hip_runtime.h>
#include <stdint.h>

// Per-row top-K magnitude masking, exact. x: (4096, 8192) fp32, K = 819.
// Exact radix select on the 31-bit abs pattern: 11 bits (2048 bins), 10, 10.
//
// Structure (R4): one wave per row, zero block barriers, wave-private LDS
// histogram, in-wave shuffle suffix scan + ballot winner pick.
// This rev (R5): PIN THE ROW IN VGPRs. R1/R3/R4 all showed VGPR_Count <=
// the raw row-buffer size (32/52/128), proving the compiler rematerialized
// the global loads each phase instead of keeping the row resident; the
// phases then re-read 64 KB/row from L2 3x (invisible in FETCH_SIZE, which
// counts HBM only). An empty asm with "+v" on every row word redefines the
// values in-register, making reload impossible. Also: fences narrowed from
// __threadfence_block (vmcnt(0)+lgkmcnt(0)) to s_waitcnt lgkmcnt(0) only --
// in-wave DS ordering needs no global drain.

constexpr int NCOLS = 8192;
constexpr int TPB   = 256;
constexpr int WAVES = TPB / 64;          // 4 rows per block, one per wave
constexpr int V4    = NCOLS / 4;
constexpr int VPL   = NCOLS / 64 / 4;    // 32 uint4 per lane

// Lane l owns a contiguous bin range stored at words [WSTR*l, WSTR*l+BPL).
// WSTR=36: byte base 144*l is 16B-aligned (b128 ok) and bank = 4*(l+j)%32
// spreads scan reads; atomic addresses spread because hot bins are
// contiguous and each 32-bin group covers all banks.
constexpr int WSTR   = 36;
constexpr int HWORDS = WSTR * 64;        // 2304 words = 9216 B per wave

__device__ __forceinline__ void lds_fence() {
  // In-wave LDS order only; do NOT drain vmcnt (global pipeline stays live).
  asm volatile("s_waitcnt lgkmcnt(0)" ::: "memory");
}

__device__ __forceinline__ uint32_t bin_addr_p1(uint32_t d) {   // 2048 bins, 32/lane
  return (uint32_t)WSTR * (d >> 5) + (d & 31u);
}
__device__ __forceinline__ uint32_t bin_addr_p23(uint32_t d) {  // 1024 bins, 16/lane
  return (uint32_t)WSTR * (d >> 4) + (d & 15u);
}

__device__ __forceinline__ void zero_hist(uint32_t* hist, int lane) {
  uint4 z = make_uint4(0u, 0u, 0u, 0u);
#pragma unroll
  for (int j = 0; j < 8; ++j)
    *(uint4*)&hist[4 * lane + 256 * j] = z;      // words 0..2047
#pragma unroll
  for (int j = 0; j < 4; ++j)
    hist[2048 + 64 * j + lane] = 0u;             // words 2048..2303
}

// Read own bins, wave suffix-scan, walk high->low for the unique bin with
// S(b) >= rem > S(b+1). Broadcast digit and updated rem via ballot+shfl.
template <int BPL>
__device__ __forceinline__ uint32_t scan_pick(const uint32_t* hist, uint32_t& rem,
                                              int lane) {
  uint32_t c[BPL];
#pragma unroll
  for (int j = 0; j < BPL / 4; ++j) {
    uint4 t = *(const uint4*)&hist[WSTR * lane + 4 * j];
    c[4 * j + 0] = t.x; c[4 * j + 1] = t.y;
    c[4 * j + 2] = t.z; c[4 * j + 3] = t.w;
  }
  uint32_t L = 0;
#pragma unroll
  for (int j = 0; j < BPL; ++j) L += c[j];

  uint32_t suf = L;                        // sum over lanes >= this lane
#pragma unroll
  for (int off = 1; off < 64; off <<= 1) {
    uint32_t o = __shfl_down(suf, off, 64);
    suf += (lane + off < 64) ? o : 0u;
  }

  uint32_t s = suf - L;                    // S at first bin above own range
  bool won = false;
  uint32_t wd = 0, wr = 0;
#pragma unroll
  for (int j = BPL - 1; j >= 0; --j) {
    uint32_t snext = s;                    // S(bin+1)
    s += c[j];                             // S(bin)
    if (s >= rem && snext < rem) {
      won = true;
      wd = (uint32_t)(lane * BPL + j);
      wr = rem - snext;
    }
  }
  uint64_t m = __ballot(won);
  int owner = __ffsll((unsigned long long)m) - 1;   // exactly one winner
  rem = (uint32_t)__shfl((int)wr, owner, 64);
  return (uint32_t)__shfl((int)wd, owner, 64);
}

__device__ __forceinline__ uint32_t phase23(uint32_t* hist, const uint4 (&v)[VPL],
                                            int dshift, int cshift, uint32_t cprefix,
                                            uint32_t& rem, int lane) {
  zero_hist(hist, lane);
  lds_fence();
#pragma unroll
  for (int j = 0; j < VPL; ++j) {
    uint32_t a[4] = {v[j].x, v[j].y, v[j].z, v[j].w};
#pragma unroll
    for (int q = 0; q < 4; ++q) {
      uint32_t key = a[q] & 0x7fffffffu;
      if ((key >> cshift) == cprefix)
        atomicAdd(&hist[bin_addr_p23((key >> dshift) & 1023u)], 1u);
    }
  }
  lds_fence();
  return scan_pick<16>(hist, rem, lane);
}

__global__ __launch_bounds__(TPB, 2) void topk_row_kernel(const float* __restrict__ x,
                                                          float* __restrict__ out,
                                                          int K, int nrows) {
  __shared__ uint32_t histAll[WAVES * HWORDS];   // 36 KB / block
  const int tid  = threadIdx.x;
  const int lane = tid & 63;
  const int wave = tid >> 6;
  const int row  = blockIdx.x * WAVES + wave;
  if (row >= nrows) return;                      // uniform per wave; no barriers used

  uint32_t* hist = &histAll[wave * HWORDS];
  const uint4* xr = (const uint4*)(x) + (size_t)row * V4;

  uint4 v[VPL];                                  // full row: 128 VGPRs
#pragma unroll
  for (int j = 0; j < VPL; ++j) v[j] = xr[lane + 64 * j];

  // PIN: redefine every row word in an opaque asm. After this, the values
  // exist only in VGPRs -- the compiler cannot rematerialize the global
  // loads for later phases (the R1/R3/R4 failure mode). Zero instructions.
#pragma unroll
  for (int j = 0; j < VPL; ++j)
    asm volatile("" : "+v"(v[j].x), "+v"(v[j].y), "+v"(v[j].z), "+v"(v[j].w));

  // Phase 1: 11-bit digit (bits 30..20), 2048 u32 bins, wave-private.
  zero_hist(hist, lane);
  lds_fence();
#pragma unroll
  for (int j = 0; j < VPL; ++j) {
    uint32_t a[4] = {v[j].x, v[j].y, v[j].z, v[j].w};
#pragma unroll
    for (int q = 0; q < 4; ++q) {
      uint32_t d = (a[q] & 0x7fffffffu) >> 20;
      atomicAdd(&hist[bin_addr_p1(d)], 1u);
    }
  }
  lds_fence();
  uint32_t rem = (uint32_t)K;
  uint32_t d1 = scan_pick<32>(hist, rem, lane);

  uint32_t d2 = phase23(hist, v, 10, 20, d1, rem, lane);
  uint32_t d3 = phase23(hist, v, 0, 10, (d1 << 10) | d2, rem, lane);

  const uint32_t thr = (d1 << 20) | (d2 << 10) | d3;   // exact K-th largest |x| bits

  uint4* outr = (uint4*)(out) + (size_t)row * V4;
#pragma unroll
  for (int j = 0; j < VPL; ++j) {
    uint4 o = v[j];
    o.x = ((o.x & 0x7fffffffu) >= thr) ? o.x : 0u;
    o.y = ((o.y & 0x7fffffffu) >= thr) ? o.y : 0u;
    o.z = ((o.z & 0x7fffffffu) >= thr) ? o.z : 0u;
    o.w = ((o.w & 0x7fffffffu) >= thr) ? o.w : 0u;
    outr[lane + 64 * j] = o;
  }
}

extern "C" void kernel_launch(void* const* d_in, const int* in_sizes, int n_in,
                              void* d_out, int out_size, void* d_ws, size_t ws_size,
                              hipStream_t stream) {
  (void)n_in; (void)out_size; (void)d_ws; (void)ws_size;
  const float* x = (const float*)d_in[0];
  float* out = (float*)d_out;
  const int rows = in_sizes[0] / NCOLS;
  const int K = (int)(0.1 * NCOLS + 0.5);  // round(819.2) = 819
  const int grid = (rows + WAVES - 1) / WAVES;
  topk_row_kernel<<<grid, TPB, 0, stream>>>(x, out, K, rows);
}

// Round 6
// 229.561 us; speedup vs baseline: 1.0689x; 1.0689x over previous
//
#include <hip/hip_runtime.h>
#include <stdint.h>

// Per-row top-K magnitude masking, exact.
// x: (4096 rows, 8192 cols) fp32. K = 819. One 256-thread block per row, row
// held in registers (8 x uint4 / thread). Exact radix select on the 31-bit
// abs bit pattern in 3 phases: 11 bits (2048 bins, u16-packed, 2 copies),
// 10 bits, 10 bits (u32, 1 copy).
//
// This rev = R1 structure + TRUE register residency. Forensics R0-R5: every
// prior rev had VGPR_Count <= raw row-buffer size -> the compiler either
// rematerialized the row loads each phase (R1: budget 64 from
// __launch_bounds__(256,8)) or parked the buffer in AGPR/scratch (R4/R5),
// adding ~3x128 MB of hidden L2/L3 traffic per dispatch; all revs landed in
// the same 83-97 us latency band. Changes vs R1, exactly two:
//   1. __launch_bounds__(256,4): VGPR budget 128 (demand ~70, headroom -> no
//      spill incentive).
//   2. asm "+v" pin on the row buffer after load (forbids remat).
// Everything else byte-identical to R1 for a clean A/B on residency.

constexpr int NCOLS = 8192;
constexpr int TPB   = 256;
constexpr int V4    = NCOLS / 4;   // 2048 uint4 per row
constexpr int VPT   = V4 / TPB;    // 8 uint4 per thread

constexpr int PAD = 8;             // words between histogram copies (bank shift)
constexpr int W1  = 1024;          // phase-1 words per copy (2048 bins, u16-packed)
constexpr int S1  = W1 + PAD;      // 1032
constexpr int C1  = 2;             // phase-1 copies (2 waves/copy)
constexpr int B2  = 1024;          // phase-2/3 bins (u32, single copy)
constexpr int S2  = B2 + PAD;      // 1032
constexpr int HW  = (C1 * S1 > S2) ? C1 * S1 : S2;   // 2064 words = 8256 B

struct Shared {
  uint32_t hist[HW];
  uint32_t wavesum[4];
  uint32_t digit;
  uint32_t rem;
};

// Suffix-scan + winner pick shared by all phases. hb[] are this thread's bin
// counts over bins [tid*BPT, tid*BPT+BPT). S(b) = #candidates with digit >= b.
// Winner: S(b) >= rem && S(b+1) < rem (unique). Updates rem to rank in bin.
template <int BPT>
__device__ __forceinline__ uint32_t pick_winner(Shared& sh, const uint32_t (&hb)[BPT],
                                                uint32_t& rem, int tid, int lane, int wave) {
  uint32_t L = 0;
#pragma unroll
  for (int j = 0; j < BPT; ++j) L += hb[j];

  // Wave-level inclusive suffix scan of L (no barriers).
  uint32_t suf = L;
#pragma unroll
  for (int off = 1; off < 64; off <<= 1) {
    uint32_t o = __shfl_down(suf, off, 64);
    suf += (lane + off < 64) ? o : 0u;
  }
  if (lane == 0) sh.wavesum[wave] = suf;   // wave total
  __syncthreads();
  uint32_t addw = 0;
#pragma unroll
  for (int w = 0; w < 4; ++w) addw += (w > wave) ? sh.wavesum[w] : 0u;
  suf += addw;  // suffix count starting at this thread's first bin

  uint32_t s = suf - L;                    // S at bin (tid+1)*BPT
#pragma unroll
  for (int j = BPT - 1; j >= 0; --j) {
    uint32_t snext = s;                    // S(bin+1)
    s += hb[j];                            // S(bin)
    if (s >= rem && snext < rem) {
      sh.digit = (uint32_t)(tid * BPT + j);
      sh.rem = rem - snext;
    }
  }
  __syncthreads();
  uint32_t d = sh.digit;
  rem = sh.rem;
  // No trailing barrier needed: next phase's first barrier (after zeroing)
  // orders these reads before any write to sh.digit/sh.rem/wavesum, and the
  // zeroing only touches hist[], whose reads completed before the wavesum
  // barrier above.
  return d;
}

// Phase 1: 11-bit digit (bits 30..20), 2048 bins, u16-packed, 2 copies.
// Packing: bin b -> word (b & 1023), halfword (b >> 10); the two halves of a
// word differ by 128 in the exponent field so they are never both hot, and
// per-copy per-half counts <= 4096 < 2^16.
__device__ __forceinline__ uint32_t phase1(Shared& sh, const uint4 (&v)[VPT],
                                           uint32_t& rem, int tid, int lane, int wave) {
  uint4* hz = (uint4*)sh.hist;
  constexpr int ZW4 = (C1 * S1) / 4;       // 516
  for (int i = tid; i < ZW4; i += TPB) hz[i] = make_uint4(0u, 0u, 0u, 0u);
  __syncthreads();

  uint32_t* h = &sh.hist[(wave >> 1) * S1];
#pragma unroll
  for (int i = 0; i < VPT; ++i) {
    uint32_t a[4] = {v[i].x, v[i].y, v[i].z, v[i].w};
#pragma unroll
    for (int j = 0; j < 4; ++j) {
      uint32_t d = (a[j] & 0x7fffffffu) >> 20;          // 11-bit digit
      atomicAdd(&h[d & (W1 - 1)], 1u << ((d >> 10) << 4));
    }
  }
  __syncthreads();

  // Combine copies; thread owns bins [tid*8, tid*8+8), all in one halfword.
  constexpr int BPT = 2048 / TPB;          // 8
  uint32_t hb[BPT];
#pragma unroll
  for (int j = 0; j < BPT; ++j) hb[j] = 0;
  const int wbase = (tid & 127) * BPT;     // word base within a copy
  const int shift = (tid >> 7) << 4;       // low half (tid<128) / high half
#pragma unroll
  for (int c = 0; c < C1; ++c) {
    const uint4* hp = (const uint4*)&sh.hist[c * S1 + wbase];
#pragma unroll
    for (int q = 0; q < BPT / 4; ++q) {
      uint4 t = hp[q];
      hb[4 * q + 0] += (t.x >> shift) & 0xffffu;
      hb[4 * q + 1] += (t.y >> shift) & 0xffffu;
      hb[4 * q + 2] += (t.z >> shift) & 0xffffu;
      hb[4 * q + 3] += (t.w >> shift) & 0xffffu;
    }
  }
  return pick_winner<BPT>(sh, hb, rem, tid, lane, wave);
}

// Phases 2/3: 10-bit digit, 1024 u32 bins, single copy (few candidates).
__device__ __forceinline__ uint32_t phase23(Shared& sh, const uint4 (&v)[VPT],
                                            int dshift, int cshift, uint32_t cprefix,
                                            uint32_t& rem, int tid, int lane, int wave) {
  uint4* hz = (uint4*)sh.hist;
  constexpr int ZW4 = S2 / 4;              // 258
  for (int i = tid; i < ZW4; i += TPB) hz[i] = make_uint4(0u, 0u, 0u, 0u);
  __syncthreads();

#pragma unroll
  for (int i = 0; i < VPT; ++i) {
    uint32_t a[4] = {v[i].x, v[i].y, v[i].z, v[i].w};
#pragma unroll
    for (int j = 0; j < 4; ++j) {
      uint32_t key = a[j] & 0x7fffffffu;
      if ((key >> cshift) == cprefix)
        atomicAdd(&sh.hist[(key >> dshift) & (B2 - 1)], 1u);
    }
  }
  __syncthreads();

  constexpr int BPT = B2 / TPB;            // 4
  uint32_t hb[BPT];
  const uint4 t = *(const uint4*)&sh.hist[tid * BPT];
  hb[0] = t.x; hb[1] = t.y; hb[2] = t.z; hb[3] = t.w;
  return pick_winner<BPT>(sh, hb, rem, tid, lane, wave);
}

__global__ __launch_bounds__(TPB, 4) void topk_row_kernel(const float* __restrict__ x,
                                                          float* __restrict__ out,
                                                          int K) {
  __shared__ Shared sh;
  const int row  = blockIdx.x;
  const int tid  = threadIdx.x;
  const int lane = tid & 63;
  const int wave = tid >> 6;

  const uint4* xr = (const uint4*)(x) + (size_t)row * V4;
  uint4 v[VPT];
#pragma unroll
  for (int i = 0; i < VPT; ++i) v[i] = xr[tid + i * TPB];

  // PIN: redefine every row word in an opaque asm -> the compiler cannot
  // rematerialize the global loads for later phases (the R1/R3 failure
  // mode: VGPR_Count <= buffer size proved the row was reloaded from L2/L3
  // each phase). With the 128-reg budget there is no spill pressure either.
#pragma unroll
  for (int i = 0; i < VPT; ++i)
    asm volatile("" : "+v"(v[i].x), "+v"(v[i].y), "+v"(v[i].z), "+v"(v[i].w));

  uint32_t rem = (uint32_t)K;
  uint32_t d1 = phase1(sh, v, rem, tid, lane, wave);
  uint32_t d2 = phase23(sh, v, 10, 20, d1, rem, tid, lane, wave);
  uint32_t d3 = phase23(sh, v,  0, 10, (d1 << 10) | d2, rem, tid, lane, wave);

  const uint32_t thr = (d1 << 20) | (d2 << 10) | d3;  // exact K-th largest |x| bits

  uint4* outr = (uint4*)(out) + (size_t)row * V4;
#pragma unroll
  for (int i = 0; i < VPT; ++i) {
    uint4 o = v[i];
    o.x = ((o.x & 0x7fffffffu) >= thr) ? o.x : 0u;
    o.y = ((o.y & 0x7fffffffu) >= thr) ? o.y : 0u;
    o.z = ((o.z & 0x7fffffffu) >= thr) ? o.z : 0u;
    o.w = ((o.w & 0x7fffffffu) >= thr) ? o.w : 0u;
    outr[tid + i * TPB] = o;
  }
}

extern "C" void kernel_launch(void* const* d_in, const int* in_sizes, int n_in,
                              void* d_out, int out_size, void* d_ws, size_t ws_size,
                              hipStream_t stream) {
  (void)n_in; (void)out_size; (void)d_ws; (void)ws_size;
  const float* x = (const float*)d_in[0];
  float* out = (float*)d_out;
  const int rows = in_sizes[0] / NCOLS;
  const int K = (int)(0.1 * NCOLS + 0.5);  // round(819.2) = 819
  topk_row_kernel<<<rows, TPB, 0, stream>>>(x, out, K);
}